// Round 1
// baseline (2022.533 us; speedup 1.0000x reference)
//
#include <hip/hip_runtime.h>
#include <hip/hip_bf16.h>

#define DM_   1024
#define NLAY  8
#define NST   16
#define KCONV 4
#define EE    2048
#define E2    4096
#define RNK   64
#define SEQ   1024
#define NXD   96
#define VOC   256
#define EPS_  1e-5f
#define NCH   32
#define CLEN  32

typedef __attribute__((ext_vector_type(8))) short bf16x8;
typedef __attribute__((ext_vector_type(4))) float f32x4;
typedef __hip_bfloat16 bf16;

__device__ __forceinline__ float sigmoidf_(float x){ return 1.f/(1.f+__expf(-x)); }
__device__ __forceinline__ float siluf_(float x){ return x*sigmoidf_(x); }
__device__ __forceinline__ float softplusf_(float x){ return (x>15.f)?x:log1pf(__expf(x)); }

// ---------------- embed ----------------
__global__ void k_embed(const int* __restrict__ ids, const float* __restrict__ emb,
                        float* __restrict__ h){
  int t = blockIdx.x;
  int v = ids[t];
  const float* src = emb + (size_t)v*DM_;
  float* dst = h + (size_t)t*DM_;
  for (int i = threadIdx.x; i < DM_; i += 256) dst[i] = src[i];
}

// ---------------- transpose f32 -> bf16 (out[c][r] = in[r][c]) ----------------
__global__ void k_transpose_bf16(const float* __restrict__ in, bf16* __restrict__ out,
                                 int rows, int cols, long in_stride, long out_stride){
  __shared__ float tile[32][33];
  const float* inp = in + (size_t)blockIdx.z * in_stride;
  bf16* outp = out + (size_t)blockIdx.z * out_stride;
  int c0 = blockIdx.x*32, r0 = blockIdx.y*32;
  int tx = threadIdx.x, ty = threadIdx.y;
#pragma unroll
  for (int j = 0; j < 4; j++)
    tile[ty + j*8][tx] = inp[(size_t)(r0 + ty + j*8)*cols + c0 + tx];
  __syncthreads();
#pragma unroll
  for (int j = 0; j < 4; j++)
    outp[(size_t)(c0 + ty + j*8)*rows + r0 + tx] = __float2bfloat16(tile[tx][ty + j*8]);
}

// ---------------- rmsnorm -> bf16 ----------------
__global__ void k_rmsnorm_bf16(const float* __restrict__ h, const float* __restrict__ w,
                               bf16* __restrict__ u){
  int t = blockIdx.x;
  const float* hp = h + (size_t)t*DM_;
  float ss = 0.f;
  for (int i = threadIdx.x; i < DM_; i += 256){ float v = hp[i]; ss += v*v; }
#pragma unroll
  for (int o = 32; o > 0; o >>= 1) ss += __shfl_down(ss, o, 64);
  __shared__ float red[4];
  if ((threadIdx.x & 63) == 0) red[threadIdx.x >> 6] = ss;
  __syncthreads();
  float tot = red[0]+red[1]+red[2]+red[3];
  float sc = rsqrtf(tot*(1.f/DM_) + EPS_);
  bf16* up = u + (size_t)t*DM_;
  for (int i = threadIdx.x; i < DM_; i += 256)
    up[i] = __float2bfloat16(hp[i]*sc*w[i]);
}

// ---------------- bf16 MFMA GEMM, A (M,K) row-major, Bt (N,K) row-major ----------------
// MODE 0: C=acc   1: C=softplus(acc+bias[col])   2: C=acc+res[idx]
template<int BM, int BN, int WM, int WN, int MODE>
__global__ __launch_bounds__(256) void k_gemm_bt(
    const short* __restrict__ A, const short* __restrict__ Bt, float* __restrict__ C,
    int M, int N, int K, const float* __restrict__ bias, const float* __restrict__ res)
{
  constexpr int BK = 32;
  constexpr int NWN = BN / WN;
  constexpr int MT = WM/16, NT = WN/16;
  constexpr int ABY = BM*BK*2, BBY = BN*BK*2;
  constexpr int ANL = (ABY + 4095)/4096, BNL = (BBY + 4095)/4096;
  __shared__ __align__(16) short As[BM*BK];
  __shared__ __align__(16) short Bs[BN*BK];
  int tid = threadIdx.x, lane = tid & 63, wave = tid >> 6;
  int wr = wave / NWN, wc = wave % NWN;
  int m0 = blockIdx.x * BM, n0 = blockIdx.y * BN;
  int lrow = lane & 15, lq = lane >> 4;

  f32x4 acc[MT][NT];
#pragma unroll
  for (int i = 0; i < MT; i++)
#pragma unroll
    for (int j = 0; j < NT; j++) acc[i][j] = (f32x4){0.f,0.f,0.f,0.f};

  for (int k0 = 0; k0 < K; k0 += BK){
    float4 areg[ANL], breg[BNL];
#pragma unroll
    for (int i = 0; i < ANL; i++){
      int off = i*4096 + tid*16;
      if (off < ABY){
        int row = off >> 6, cb = off & 63;
        areg[i] = *(const float4*)(A + (size_t)(m0+row)*K + k0 + (cb>>1));
      }
    }
#pragma unroll
    for (int i = 0; i < BNL; i++){
      int off = i*4096 + tid*16;
      if (off < BBY){
        int row = off >> 6, cb = off & 63;
        breg[i] = *(const float4*)(Bt + (size_t)(n0+row)*K + k0 + (cb>>1));
      }
    }
    __syncthreads();   // previous iteration's LDS reads done
#pragma unroll
    for (int i = 0; i < ANL; i++){
      int off = i*4096 + tid*16;
      if (off < ABY) *(float4*)((char*)As + off) = areg[i];
    }
#pragma unroll
    for (int i = 0; i < BNL; i++){
      int off = i*4096 + tid*16;
      if (off < BBY) *(float4*)((char*)Bs + off) = breg[i];
    }
    __syncthreads();
    bf16x8 af[MT], bfr[NT];
#pragma unroll
    for (int mt = 0; mt < MT; mt++)
      af[mt] = *(const bf16x8*)(As + (wr*WM + mt*16 + lrow)*BK + lq*8);
#pragma unroll
    for (int nt = 0; nt < NT; nt++)
      bfr[nt] = *(const bf16x8*)(Bs + (wc*WN + nt*16 + lrow)*BK + lq*8);
#pragma unroll
    for (int mt = 0; mt < MT; mt++)
#pragma unroll
      for (int nt = 0; nt < NT; nt++)
        acc[mt][nt] = __builtin_amdgcn_mfma_f32_16x16x32_bf16(af[mt], bfr[nt], acc[mt][nt], 0,0,0);
  }
#pragma unroll
  for (int mt = 0; mt < MT; mt++){
    int row = m0 + wr*WM + mt*16 + lq*4;
#pragma unroll
    for (int nt = 0; nt < NT; nt++){
      int col = n0 + wc*WN + nt*16 + lrow;
#pragma unroll
      for (int r = 0; r < 4; r++){
        float v = acc[mt][nt][r];
        size_t idx = (size_t)(row + r)*N + col;
        if (MODE == 1) v = softplusf_(v + bias[col]);
        else if (MODE == 2) v = v + res[idx];
        C[idx] = v;
      }
    }
  }
}

// ---------------- causal depthwise conv(K=4) + bias + silu ----------------
__global__ void k_conv_silu(const float* __restrict__ xz, const float* __restrict__ cw,
                            const float* __restrict__ cb, float* __restrict__ xact,
                            bf16* __restrict__ xbf){
  int t = blockIdx.y;
  int e = blockIdx.x*256 + threadIdx.x;
  float4 w4 = *(const float4*)(cw + (size_t)e*4);
  float acc = cb[e];
  if (t >= 3){
    acc += xz[(size_t)(t-3)*E2 + e]*w4.x + xz[(size_t)(t-2)*E2 + e]*w4.y
         + xz[(size_t)(t-1)*E2 + e]*w4.z + xz[(size_t)t*E2 + e]*w4.w;
  } else {
    const float* wp = (const float*)&w4;
#pragma unroll
    for (int k = 0; k < 4; k++){ int tt = t-3+k; if (tt >= 0) acc += xz[(size_t)tt*E2 + e]*wp[k]; }
  }
  float xv = siluf_(acc);
  xact[(size_t)t*EE + e] = xv;
  xbf[(size_t)t*EE + e] = __float2bfloat16(xv);
}

// ---------------- cast xdbl[:, :64] -> bf16 ----------------
__global__ void k_cast_dtproj(const float* __restrict__ xdbl, bf16* __restrict__ out){
  int t = blockIdx.x;
  out[(size_t)t*RNK + threadIdx.x] = __float2bfloat16(xdbl[(size_t)t*NXD + threadIdx.x]);
}

// ---------------- scan phase A: per-(e,chunk) local scan from h=0 ----------------
__global__ void k_scanA(const float* __restrict__ dt, const float* __restrict__ x,
                        const float* __restrict__ xdbl, const float* __restrict__ Alog,
                        float* __restrict__ S, float* __restrict__ dtsum){
  int e = blockIdx.x*256 + threadIdx.x;
  int c = blockIdx.y;
  int t0 = c*CLEN;
  float Ae[NST];
#pragma unroll
  for (int n = 0; n < NST; n++) Ae[n] = -__expf(Alog[(size_t)e*NST + n]);
  __shared__ float Bsm[CLEN][NST];
  for (int i = threadIdx.x; i < CLEN*NST; i += 256)
    Bsm[i>>4][i&15] = xdbl[(size_t)(t0 + (i>>4))*NXD + RNK + (i&15)];
  __syncthreads();
  float h[NST];
#pragma unroll
  for (int n = 0; n < NST; n++) h[n] = 0.f;
  float ds = 0.f;
  for (int tt = 0; tt < CLEN; tt++){
    float dtv = dt[(size_t)(t0+tt)*EE + e];
    float xv  = x[(size_t)(t0+tt)*EE + e];
    ds += dtv;
    float sx = dtv * xv;
#pragma unroll
    for (int n = 0; n < NST; n++)
      h[n] = __expf(dtv*Ae[n])*h[n] + sx*Bsm[tt][n];
  }
  float* Sp = S + ((size_t)c*EE + e)*NST;
#pragma unroll
  for (int n = 0; n < NST; n++) Sp[n] = h[n];
  dtsum[(size_t)c*EE + e] = ds;
}

// ---------------- scan phase B: sequential stitch over chunks ----------------
__global__ void k_scanB(const float* __restrict__ S, const float* __restrict__ dtsum,
                        const float* __restrict__ Alog, float* __restrict__ hinit){
  int idx = blockIdx.x*256 + threadIdx.x;   // e*16+n
  float An = -__expf(Alog[idx]);
  int e = idx >> 4;
  float h = 0.f;
  for (int c = 0; c < NCH; c++){
    hinit[(size_t)c*EE*NST + idx] = h;
    h = __expf(dtsum[(size_t)c*EE + e]*An)*h + S[(size_t)c*EE*NST + idx];
  }
}

// ---------------- scan phase C: recompute with init, y = h.C + D x, gate silu(z) ----------------
__global__ void k_scanC(const float* __restrict__ dt, const float* __restrict__ x,
                        const float* __restrict__ xdbl, const float* __restrict__ Alog,
                        const float* __restrict__ Dp, const float* __restrict__ hinit,
                        const float* __restrict__ xz, bf16* __restrict__ ybf){
  int e = blockIdx.x*256 + threadIdx.x;
  int c = blockIdx.y;
  int t0 = c*CLEN;
  float Ae[NST];
#pragma unroll
  for (int n = 0; n < NST; n++) Ae[n] = -__expf(Alog[(size_t)e*NST + n]);
  __shared__ float Bsm[CLEN][NST], Csm[CLEN][NST];
  for (int i = threadIdx.x; i < CLEN*NST; i += 256){
    int tt = i>>4, n = i&15;
    Bsm[tt][n] = xdbl[(size_t)(t0+tt)*NXD + RNK + n];
    Csm[tt][n] = xdbl[(size_t)(t0+tt)*NXD + RNK + NST + n];
  }
  __syncthreads();
  float h[NST];
  const float* hp = hinit + ((size_t)c*EE + e)*NST;
#pragma unroll
  for (int n = 0; n < NST; n++) h[n] = hp[n];
  float Dv = Dp[e];
  for (int tt = 0; tt < CLEN; tt++){
    float dtv = dt[(size_t)(t0+tt)*EE + e];
    float xv  = x[(size_t)(t0+tt)*EE + e];
    float sx = dtv*xv;
    float y = Dv*xv;
#pragma unroll
    for (int n = 0; n < NST; n++){
      h[n] = __expf(dtv*Ae[n])*h[n] + sx*Bsm[tt][n];
      y += h[n]*Csm[tt][n];
    }
    float zv = xz[(size_t)(t0+tt)*E2 + EE + e];
    y *= zv*sigmoidf_(zv);
    ybf[(size_t)(t0+tt)*EE + e] = __float2bfloat16(y);
  }
}

// ---------------- launch ----------------
extern "C" void kernel_launch(void* const* d_in, const int* in_sizes, int n_in,
                              void* d_out, int out_size, void* d_ws, size_t ws_size,
                              hipStream_t stream)
{
  const int*   ids  = (const int*)d_in[0];
  const float* emb  = (const float*)d_in[1];
  const float* Wxz  = (const float*)d_in[2];
  const float* cw   = (const float*)d_in[3];
  const float* cb   = (const float*)d_in[4];
  const float* Wx   = (const float*)d_in[5];
  const float* Wdt  = (const float*)d_in[6];
  const float* dtb  = (const float*)d_in[7];
  const float* Alog = (const float*)d_in[8];
  const float* Dp   = (const float*)d_in[9];
  const float* Wout = (const float*)d_in[10];
  const float* nw   = (const float*)d_in[11];
  const float* fnw  = (const float*)d_in[12];
  const float* lmw  = (const float*)d_in[13];

  char* p = (char*)d_ws;
  auto alloc = [&](size_t bytes){ void* r = (void*)p; p += (bytes + 255) & ~(size_t)255; return r; };
  bf16* wxz_bf  = (bf16*)alloc((size_t)NLAY*E2*DM_*2);
  bf16* wout_bf = (bf16*)alloc((size_t)NLAY*DM_*EE*2);
  bf16* wx_bf   = (bf16*)alloc((size_t)NLAY*NXD*EE*2);
  bf16* wdt_bf  = (bf16*)alloc((size_t)NLAY*EE*RNK*2);
  bf16* lm_bf   = (bf16*)alloc((size_t)VOC*DM_*2);
  float* hA     = (float*)alloc((size_t)SEQ*DM_*4);
  float* hB     = (float*)alloc((size_t)SEQ*DM_*4);
  bf16* u_bf    = (bf16*)alloc((size_t)SEQ*DM_*2);
  float* xzb    = (float*)alloc((size_t)SEQ*E2*4);
  float* xact   = (float*)alloc((size_t)SEQ*EE*4);
  bf16* x_bf    = (bf16*)alloc((size_t)SEQ*EE*2);
  float* xdbl   = (float*)alloc((size_t)SEQ*NXD*4);
  bf16* xd64    = (bf16*)alloc((size_t)SEQ*RNK*2);
  float* dtbuf  = (float*)alloc((size_t)SEQ*EE*4);
  float* Sbuf   = (float*)alloc((size_t)NCH*EE*NST*4);
  float* dtsum  = (float*)alloc((size_t)NCH*EE*4);
  float* hinit  = (float*)alloc((size_t)NCH*EE*NST*4);
  bf16* y_bf    = (bf16*)alloc((size_t)SEQ*EE*2);

  // weight conversion (per launch; weights -> bf16 B^T layout)
  k_transpose_bf16<<<dim3(E2/32, DM_/32, NLAY), dim3(32,8), 0, stream>>>(Wxz, wxz_bf, DM_, E2, (long)DM_*E2, (long)E2*DM_);
  k_transpose_bf16<<<dim3(DM_/32, EE/32, NLAY), dim3(32,8), 0, stream>>>(Wout, wout_bf, EE, DM_, (long)EE*DM_, (long)DM_*EE);
  k_transpose_bf16<<<dim3(NXD/32, EE/32, NLAY), dim3(32,8), 0, stream>>>(Wx, wx_bf, EE, NXD, (long)EE*NXD, (long)NXD*EE);
  k_transpose_bf16<<<dim3(EE/32, RNK/32, NLAY), dim3(32,8), 0, stream>>>(Wdt, wdt_bf, RNK, EE, (long)RNK*EE, (long)EE*RNK);
  k_transpose_bf16<<<dim3(VOC/32, DM_/32, 1), dim3(32,8), 0, stream>>>(lmw, lm_bf, DM_, VOC, 0, 0);

  k_embed<<<SEQ, 256, 0, stream>>>(ids, emb, hA);

  float* hcur = hA; float* hnxt = hB;
  for (int l = 0; l < NLAY; l++){
    k_rmsnorm_bf16<<<SEQ, 256, 0, stream>>>(hcur, nw + (size_t)l*DM_, u_bf);
    k_gemm_bt<128,128,64,64,0><<<dim3(SEQ/128, E2/128), 256, 0, stream>>>(
        (const short*)u_bf, (const short*)(wxz_bf + (size_t)l*E2*DM_), xzb, SEQ, E2, DM_, nullptr, nullptr);
    k_conv_silu<<<dim3(EE/256, SEQ), 256, 0, stream>>>(
        xzb, cw + (size_t)l*EE*KCONV, cb + (size_t)l*EE, xact, x_bf);
    k_gemm_bt<64,96,32,48,0><<<dim3(SEQ/64, 1), 256, 0, stream>>>(
        (const short*)x_bf, (const short*)(wx_bf + (size_t)l*NXD*EE), xdbl, SEQ, NXD, EE, nullptr, nullptr);
    k_cast_dtproj<<<SEQ, RNK, 0, stream>>>(xdbl, xd64);
    k_gemm_bt<64,64,32,32,1><<<dim3(SEQ/64, EE/64), 256, 0, stream>>>(
        (const short*)xd64, (const short*)(wdt_bf + (size_t)l*EE*RNK), dtbuf, SEQ, EE, RNK,
        dtb + (size_t)l*EE, nullptr);
    k_scanA<<<dim3(EE/256, NCH), 256, 0, stream>>>(
        dtbuf, xact, xdbl, Alog + (size_t)l*EE*NST, Sbuf, dtsum);
    k_scanB<<<dim3(EE*NST/256), 256, 0, stream>>>(Sbuf, dtsum, Alog + (size_t)l*EE*NST, hinit);
    k_scanC<<<dim3(EE/256, NCH), 256, 0, stream>>>(
        dtbuf, xact, xdbl, Alog + (size_t)l*EE*NST, Dp + (size_t)l*EE, hinit, xzb, y_bf);
    k_gemm_bt<64,64,32,32,2><<<dim3(SEQ/64, DM_/64), 256, 0, stream>>>(
        (const short*)y_bf, (const short*)(wout_bf + (size_t)l*DM_*EE), hnxt, SEQ, DM_, EE,
        nullptr, hcur);
    float* tmp = hcur; hcur = hnxt; hnxt = tmp;
  }
  k_rmsnorm_bf16<<<SEQ, 256, 0, stream>>>(hcur, fnw, u_bf);
  k_gemm_bt<64,64,32,32,0><<<dim3(SEQ/64, VOC/64), 256, 0, stream>>>(
      (const short*)u_bf, (const short*)lm_bf, (float*)d_out, SEQ, VOC, DM_, nullptr, nullptr);
}

// Round 2
// 1303.014 us; speedup vs baseline: 1.5522x; 1.5522x over previous
//
#include <hip/hip_runtime.h>
#include <hip/hip_bf16.h>

#define DM_   1024
#define NLAY  8
#define NST   16
#define KCONV 4
#define EE    2048
#define E2    4096
#define RNK   64
#define SEQ   1024
#define NXD   96
#define VOC   256
#define EPS_  1e-5f
#define NCH   32
#define CLEN  32

typedef __attribute__((ext_vector_type(8))) short bf16x8;
typedef __attribute__((ext_vector_type(4))) float f32x4;
typedef __hip_bfloat16 bf16;

__device__ __forceinline__ float sigmoidf_(float x){ return 1.f/(1.f+__expf(-x)); }
__device__ __forceinline__ float siluf_(float x){ return x*sigmoidf_(x); }
__device__ __forceinline__ float softplusf_(float x){ return (x>15.f)?x:log1pf(__expf(x)); }

__device__ __forceinline__ void gld_lds16(const short* g, short* lds_uniform){
  __builtin_amdgcn_global_load_lds(
      (const __attribute__((address_space(1))) unsigned int*)(const void*)g,
      (__attribute__((address_space(3))) unsigned int*)(void*)lds_uniform,
      16, 0, 0);
}

// ---------------- embed ----------------
__global__ void k_embed(const int* __restrict__ ids, const float* __restrict__ emb,
                        float* __restrict__ h){
  int t = blockIdx.x;
  int v = ids[t];
  const float* src = emb + (size_t)v*DM_;
  float* dst = h + (size_t)t*DM_;
  for (int i = threadIdx.x; i < DM_; i += 256) dst[i] = src[i];
}

// ---------------- transpose f32 -> bf16 (out[c][r] = in[r][c]) ----------------
__global__ void k_transpose_bf16(const float* __restrict__ in, bf16* __restrict__ out,
                                 int rows, int cols, long in_stride, long out_stride){
  __shared__ float tile[32][33];
  const float* inp = in + (size_t)blockIdx.z * in_stride;
  bf16* outp = out + (size_t)blockIdx.z * out_stride;
  int c0 = blockIdx.x*32, r0 = blockIdx.y*32;
  int tx = threadIdx.x, ty = threadIdx.y;
#pragma unroll
  for (int j = 0; j < 4; j++)
    tile[ty + j*8][tx] = inp[(size_t)(r0 + ty + j*8)*cols + c0 + tx];
  __syncthreads();
#pragma unroll
  for (int j = 0; j < 4; j++)
    outp[(size_t)(c0 + ty + j*8)*rows + r0 + tx] = __float2bfloat16(tile[tx][ty + j*8]);
}

// ---------------- rmsnorm -> bf16 ----------------
__global__ void k_rmsnorm_bf16(const float* __restrict__ h, const float* __restrict__ w,
                               bf16* __restrict__ u){
  int t = blockIdx.x;
  const float* hp = h + (size_t)t*DM_;
  float ss = 0.f;
  for (int i = threadIdx.x; i < DM_; i += 256){ float v = hp[i]; ss += v*v; }
#pragma unroll
  for (int o = 32; o > 0; o >>= 1) ss += __shfl_down(ss, o, 64);
  __shared__ float red[4];
  if ((threadIdx.x & 63) == 0) red[threadIdx.x >> 6] = ss;
  __syncthreads();
  float tot = red[0]+red[1]+red[2]+red[3];
  float sc = rsqrtf(tot*(1.f/DM_) + EPS_);
  bf16* up = u + (size_t)t*DM_;
  for (int i = threadIdx.x; i < DM_; i += 256)
    up[i] = __float2bfloat16(hp[i]*sc*w[i]);
}

// ---------------- bf16 MFMA GEMM, double-buffered LDS via global_load_lds ----------------
// A (M,K) row-major bf16, Bt (N,K) row-major bf16, C (M,N) f32.
// BK=64, XOR-swizzled LDS (chunk c holds global k-chunk c^(row&7)) -> conflict-free reads.
// MODE 0: C=acc   1: C=softplus(acc+bias[col])   3: atomicAdd(C,acc [+res if z==0]) (split-K)
template<int BM, int BN, int NWM, int NWN, int MODE>
__global__ __launch_bounds__(256,1) void k_gemm(
    const short* __restrict__ A, const short* __restrict__ Bt, float* __restrict__ C,
    int M, int N, int K, int Ksplit,
    const float* __restrict__ bias, const float* __restrict__ res)
{
  constexpr int BK = 64;
  constexpr int WM = BM/NWM, WN = BN/NWN;
  constexpr int MT = WM/16, NT = WN/16;
  constexpr int ABY = BM*BK*2, BBY = BN*BK*2;
  constexpr int AISS = ABY/4096, BISS = BBY/4096;   // 256 thr x 16B = 4096 B per issue
  __shared__ __align__(16) short As[2][BM*BK];
  __shared__ __align__(16) short Bs[2][BN*BK];
  int tid = threadIdx.x, lane = tid & 63, wave = tid >> 6;
  int wr = wave / NWN, wc = wave % NWN;
  int m0 = blockIdx.x * BM, n0 = blockIdx.y * BN;
  int lrow = lane & 15, lq = lane >> 4;
  int wbase = (tid & ~63) * 16;   // wave-uniform byte base within a 4096B issue

  int kbeg = blockIdx.z * Ksplit;
  int nk = Ksplit / BK;

  f32x4 acc[MT][NT];
#pragma unroll
  for (int i = 0; i < MT; i++)
#pragma unroll
    for (int j = 0; j < NT; j++) acc[i][j] = (f32x4){0.f,0.f,0.f,0.f};

  auto stage = [&](int k0, int buf){
#pragma unroll
    for (int i = 0; i < AISS; i++){
      int off = i*4096 + tid*16;
      int row = off >> 7;
      int kc  = ((off >> 4) & 7) ^ (row & 7);
      gld_lds16(A + (size_t)(m0+row)*K + k0 + kc*8,
                As[buf] + ((i*4096 + wbase) >> 1));
    }
#pragma unroll
    for (int i = 0; i < BISS; i++){
      int off = i*4096 + tid*16;
      int row = off >> 7;
      int kc  = ((off >> 4) & 7) ^ (row & 7);
      gld_lds16(Bt + (size_t)(n0+row)*K + k0 + kc*8,
                Bs[buf] + ((i*4096 + wbase) >> 1));
    }
  };

  stage(kbeg, 0);
  __syncthreads();
  for (int it = 0; it < nk; it++){
    int cur = it & 1;
    if (it + 1 < nk) stage(kbeg + (it+1)*BK, cur ^ 1);
#pragma unroll
    for (int s = 0; s < 2; s++){
      bf16x8 af[MT], bfr[NT];
#pragma unroll
      for (int mt = 0; mt < MT; mt++){
        int row = wr*WM + mt*16 + lrow;
        int cc = (s*4 + lq) ^ (row & 7);
        af[mt] = *(const bf16x8*)(As[cur] + row*BK + cc*8);
      }
#pragma unroll
      for (int nt = 0; nt < NT; nt++){
        int row = wc*WN + nt*16 + lrow;
        int cc = (s*4 + lq) ^ (row & 7);
        bfr[nt] = *(const bf16x8*)(Bs[cur] + row*BK + cc*8);
      }
#pragma unroll
      for (int mt = 0; mt < MT; mt++)
#pragma unroll
        for (int nt = 0; nt < NT; nt++)
          acc[mt][nt] = __builtin_amdgcn_mfma_f32_16x16x32_bf16(af[mt], bfr[nt], acc[mt][nt], 0,0,0);
    }
    __syncthreads();
  }

#pragma unroll
  for (int mt = 0; mt < MT; mt++){
    int row = m0 + wr*WM + mt*16 + lq*4;
#pragma unroll
    for (int nt = 0; nt < NT; nt++){
      int col = n0 + wc*WN + nt*16 + lrow;
#pragma unroll
      for (int r = 0; r < 4; r++){
        float v = acc[mt][nt][r];
        size_t idx = (size_t)(row + r)*N + col;
        if (MODE == 1){ C[idx] = softplusf_(v + bias[col]); }
        else if (MODE == 3){
          if (res && blockIdx.z == 0) v += res[idx];
          atomicAdd(&C[idx], v);
        } else { C[idx] = v; }
      }
    }
  }
}

// ---------------- causal depthwise conv(K=4) + bias + silu ----------------
__global__ void k_conv_silu(const float* __restrict__ xz, const float* __restrict__ cw,
                            const float* __restrict__ cb, float* __restrict__ xact,
                            bf16* __restrict__ xbf){
  int t = blockIdx.y;
  int e = blockIdx.x*256 + threadIdx.x;
  float4 w4 = *(const float4*)(cw + (size_t)e*4);
  float acc = cb[e];
  if (t >= 3){
    acc += xz[(size_t)(t-3)*E2 + e]*w4.x + xz[(size_t)(t-2)*E2 + e]*w4.y
         + xz[(size_t)(t-1)*E2 + e]*w4.z + xz[(size_t)t*E2 + e]*w4.w;
  } else {
    const float* wp = (const float*)&w4;
#pragma unroll
    for (int k = 0; k < 4; k++){ int tt = t-3+k; if (tt >= 0) acc += xz[(size_t)tt*E2 + e]*wp[k]; }
  }
  float xv = siluf_(acc);
  xact[(size_t)t*EE + e] = xv;
  xbf[(size_t)t*EE + e] = __float2bfloat16(xv);
}

// ---------------- cast xdbl[:, :64] -> bf16 ----------------
__global__ void k_cast_dtproj(const float* __restrict__ xdbl, bf16* __restrict__ out){
  int t = blockIdx.x;
  out[(size_t)t*RNK + threadIdx.x] = __float2bfloat16(xdbl[(size_t)t*NXD + threadIdx.x]);
}

// ---------------- scan phase A: per-(e,chunk) local scan from h=0 ----------------
__global__ void k_scanA(const float* __restrict__ dt, const float* __restrict__ x,
                        const float* __restrict__ xdbl, const float* __restrict__ Alog,
                        float* __restrict__ S, float* __restrict__ dtsum){
  int e = blockIdx.x*256 + threadIdx.x;
  int c = blockIdx.y;
  int t0 = c*CLEN;
  float Ae[NST];
#pragma unroll
  for (int n = 0; n < NST; n++) Ae[n] = -__expf(Alog[(size_t)e*NST + n]);
  __shared__ float Bsm[CLEN][NST];
  for (int i = threadIdx.x; i < CLEN*NST; i += 256)
    Bsm[i>>4][i&15] = xdbl[(size_t)(t0 + (i>>4))*NXD + RNK + (i&15)];
  __syncthreads();
  float h[NST];
#pragma unroll
  for (int n = 0; n < NST; n++) h[n] = 0.f;
  float ds = 0.f;
  for (int tt = 0; tt < CLEN; tt++){
    float dtv = dt[(size_t)(t0+tt)*EE + e];
    float xv  = x[(size_t)(t0+tt)*EE + e];
    ds += dtv;
    float sx = dtv * xv;
#pragma unroll
    for (int n = 0; n < NST; n++)
      h[n] = __expf(dtv*Ae[n])*h[n] + sx*Bsm[tt][n];
  }
  float* Sp = S + ((size_t)c*EE + e)*NST;
#pragma unroll
  for (int n = 0; n < NST; n++) Sp[n] = h[n];
  dtsum[(size_t)c*EE + e] = ds;
}

// ---------------- scan phase B: sequential stitch over chunks ----------------
__global__ void k_scanB(const float* __restrict__ S, const float* __restrict__ dtsum,
                        const float* __restrict__ Alog, float* __restrict__ hinit){
  int idx = blockIdx.x*256 + threadIdx.x;   // e*16+n
  float An = -__expf(Alog[idx]);
  int e = idx >> 4;
  float h = 0.f;
  for (int c = 0; c < NCH; c++){
    hinit[(size_t)c*EE*NST + idx] = h;
    h = __expf(dtsum[(size_t)c*EE + e]*An)*h + S[(size_t)c*EE*NST + idx];
  }
}

// ---------------- scan phase C: recompute with init, y = h.C + D x, gate silu(z) ----------------
__global__ void k_scanC(const float* __restrict__ dt, const float* __restrict__ x,
                        const float* __restrict__ xdbl, const float* __restrict__ Alog,
                        const float* __restrict__ Dp, const float* __restrict__ hinit,
                        const float* __restrict__ xz, bf16* __restrict__ ybf){
  int e = blockIdx.x*256 + threadIdx.x;
  int c = blockIdx.y;
  int t0 = c*CLEN;
  float Ae[NST];
#pragma unroll
  for (int n = 0; n < NST; n++) Ae[n] = -__expf(Alog[(size_t)e*NST + n]);
  __shared__ float Bsm[CLEN][NST], Csm[CLEN][NST];
  for (int i = threadIdx.x; i < CLEN*NST; i += 256){
    int tt = i>>4, n = i&15;
    Bsm[tt][n] = xdbl[(size_t)(t0+tt)*NXD + RNK + n];
    Csm[tt][n] = xdbl[(size_t)(t0+tt)*NXD + RNK + NST + n];
  }
  __syncthreads();
  float h[NST];
  const float* hp = hinit + ((size_t)c*EE + e)*NST;
#pragma unroll
  for (int n = 0; n < NST; n++) h[n] = hp[n];
  float Dv = Dp[e];
  for (int tt = 0; tt < CLEN; tt++){
    float dtv = dt[(size_t)(t0+tt)*EE + e];
    float xv  = x[(size_t)(t0+tt)*EE + e];
    float sx = dtv*xv;
    float y = Dv*xv;
#pragma unroll
    for (int n = 0; n < NST; n++){
      h[n] = __expf(dtv*Ae[n])*h[n] + sx*Bsm[tt][n];
      y += h[n]*Csm[tt][n];
    }
    float zv = xz[(size_t)(t0+tt)*E2 + EE + e];
    y *= zv*sigmoidf_(zv);
    ybf[(size_t)(t0+tt)*EE + e] = __float2bfloat16(y);
  }
}

// ---------------- launch ----------------
extern "C" void kernel_launch(void* const* d_in, const int* in_sizes, int n_in,
                              void* d_out, int out_size, void* d_ws, size_t ws_size,
                              hipStream_t stream)
{
  const int*   ids  = (const int*)d_in[0];
  const float* emb  = (const float*)d_in[1];
  const float* Wxz  = (const float*)d_in[2];
  const float* cw   = (const float*)d_in[3];
  const float* cb   = (const float*)d_in[4];
  const float* Wx   = (const float*)d_in[5];
  const float* Wdt  = (const float*)d_in[6];
  const float* dtb  = (const float*)d_in[7];
  const float* Alog = (const float*)d_in[8];
  const float* Dp   = (const float*)d_in[9];
  const float* Wout = (const float*)d_in[10];
  const float* nw   = (const float*)d_in[11];
  const float* fnw  = (const float*)d_in[12];
  const float* lmw  = (const float*)d_in[13];

  char* p = (char*)d_ws;
  auto alloc = [&](size_t bytes){ void* r = (void*)p; p += (bytes + 255) & ~(size_t)255; return r; };
  bf16* wxz_bf  = (bf16*)alloc((size_t)NLAY*E2*DM_*2);
  bf16* wout_bf = (bf16*)alloc((size_t)NLAY*DM_*EE*2);
  bf16* wx_bf   = (bf16*)alloc((size_t)NLAY*NXD*EE*2);
  bf16* wdt_bf  = (bf16*)alloc((size_t)NLAY*EE*RNK*2);
  bf16* lm_bf   = (bf16*)alloc((size_t)VOC*DM_*2);
  float* hA     = (float*)alloc((size_t)SEQ*DM_*4);
  float* hB     = (float*)alloc((size_t)SEQ*DM_*4);
  bf16* u_bf    = (bf16*)alloc((size_t)SEQ*DM_*2);
  float* xzb    = (float*)alloc((size_t)SEQ*E2*4);
  float* xact   = (float*)alloc((size_t)SEQ*EE*4);
  bf16* x_bf    = (bf16*)alloc((size_t)SEQ*EE*2);
  float* xdbl   = (float*)alloc((size_t)SEQ*NXD*4);
  bf16* xd64    = (bf16*)alloc((size_t)SEQ*RNK*2);
  float* dtbuf  = (float*)alloc((size_t)SEQ*EE*4);
  float* Sbuf   = (float*)alloc((size_t)NCH*EE*NST*4);
  float* dtsum  = (float*)alloc((size_t)NCH*EE*4);
  float* hinit  = (float*)alloc((size_t)NCH*EE*NST*4);
  bf16* y_bf    = (bf16*)alloc((size_t)SEQ*EE*2);

  // weight conversion (per launch; weights -> bf16 B^T layout)
  k_transpose_bf16<<<dim3(E2/32, DM_/32, NLAY), dim3(32,8), 0, stream>>>(Wxz, wxz_bf, DM_, E2, (long)DM_*E2, (long)E2*DM_);
  k_transpose_bf16<<<dim3(DM_/32, EE/32, NLAY), dim3(32,8), 0, stream>>>(Wout, wout_bf, EE, DM_, (long)EE*DM_, (long)DM_*EE);
  k_transpose_bf16<<<dim3(NXD/32, EE/32, NLAY), dim3(32,8), 0, stream>>>(Wx, wx_bf, EE, NXD, (long)EE*NXD, (long)NXD*EE);
  k_transpose_bf16<<<dim3(EE/32, RNK/32, NLAY), dim3(32,8), 0, stream>>>(Wdt, wdt_bf, RNK, EE, (long)RNK*EE, (long)EE*RNK);
  k_transpose_bf16<<<dim3(VOC/32, DM_/32, 1), dim3(32,8), 0, stream>>>(lmw, lm_bf, DM_, VOC, 0, 0);

  k_embed<<<SEQ, 256, 0, stream>>>(ids, emb, hA);

  float* hcur = hA; float* hnxt = hB;
  for (int l = 0; l < NLAY; l++){
    hipMemsetAsync(hnxt, 0, (size_t)SEQ*DM_*4, stream);
    k_rmsnorm_bf16<<<SEQ, 256, 0, stream>>>(hcur, nw + (size_t)l*DM_, u_bf);
    k_gemm<128,128,2,2,0><<<dim3(SEQ/128, E2/128, 1), 256, 0, stream>>>(
        (const short*)u_bf, (const short*)(wxz_bf + (size_t)l*E2*DM_), xzb,
        SEQ, E2, DM_, DM_, nullptr, nullptr);
    k_conv_silu<<<dim3(EE/256, SEQ), 256, 0, stream>>>(
        xzb, cw + (size_t)l*EE*KCONV, cb + (size_t)l*EE, xact, x_bf);
    hipMemsetAsync(xdbl, 0, (size_t)SEQ*NXD*4, stream);
    k_gemm<64,96,2,2,3><<<dim3(SEQ/64, 1, 8), 256, 0, stream>>>(
        (const short*)x_bf, (const short*)(wx_bf + (size_t)l*NXD*EE), xdbl,
        SEQ, NXD, EE, EE/8, nullptr, nullptr);
    k_cast_dtproj<<<SEQ, RNK, 0, stream>>>(xdbl, xd64);
    k_gemm<64,64,2,2,1><<<dim3(SEQ/64, EE/64, 1), 256, 0, stream>>>(
        (const short*)xd64, (const short*)(wdt_bf + (size_t)l*EE*RNK), dtbuf,
        SEQ, EE, RNK, RNK, dtb + (size_t)l*EE, nullptr);
    k_scanA<<<dim3(EE/256, NCH), 256, 0, stream>>>(
        dtbuf, xact, xdbl, Alog + (size_t)l*EE*NST, Sbuf, dtsum);
    k_scanB<<<dim3(EE*NST/256), 256, 0, stream>>>(Sbuf, dtsum, Alog + (size_t)l*EE*NST, hinit);
    k_scanC<<<dim3(EE/256, NCH), 256, 0, stream>>>(
        dtbuf, xact, xdbl, Alog + (size_t)l*EE*NST, Dp + (size_t)l*EE, hinit, xzb, y_bf);
    k_gemm<64,64,2,2,3><<<dim3(SEQ/64, DM_/64, 2), 256, 0, stream>>>(
        (const short*)y_bf, (const short*)(wout_bf + (size_t)l*DM_*EE), hnxt,
        SEQ, DM_, EE, EE/2, nullptr, hcur);
    float* tmp = hcur; hcur = hnxt; hnxt = tmp;
  }
  k_rmsnorm_bf16<<<SEQ, 256, 0, stream>>>(hcur, fnw, u_bf);
  hipMemsetAsync(d_out, 0, (size_t)SEQ*VOC*4, stream);
  k_gemm<64,64,2,2,3><<<dim3(SEQ/64, VOC/64, 4), 256, 0, stream>>>(
      (const short*)u_bf, (const short*)lm_bf, (float*)d_out,
      SEQ, VOC, DM_, DM_/4, nullptr, nullptr);
}

// Round 3
// 1164.498 us; speedup vs baseline: 1.7368x; 1.1189x over previous
//
#include <hip/hip_runtime.h>
#include <hip/hip_bf16.h>

#define DM_   1024
#define NLAY  8
#define NST   16
#define KCONV 4
#define EE    2048
#define E2    4096
#define RNK   64
#define SEQ   1024
#define NXD   96
#define VOC   256
#define EPS_  1e-5f
#define NCH   32
#define CLEN  32

typedef __attribute__((ext_vector_type(8))) short bf16x8;
typedef __attribute__((ext_vector_type(4))) float f32x4;
typedef __hip_bfloat16 bf16;

__device__ __forceinline__ float sigmoidf_(float x){ return 1.f/(1.f+__expf(-x)); }
__device__ __forceinline__ float siluf_(float x){ return x*sigmoidf_(x); }
__device__ __forceinline__ float softplusf_(float x){ return (x>15.f)?x:log1pf(__expf(x)); }

__device__ __forceinline__ void gld_lds16(const short* g, short* lds_uniform){
  __builtin_amdgcn_global_load_lds(
      (const __attribute__((address_space(1))) unsigned int*)(const void*)g,
      (__attribute__((address_space(3))) unsigned int*)(void*)lds_uniform,
      16, 0, 0);
}

// ---------------- transpose f32 -> bf16 (out[c][r] = in[r][c]) ----------------
__global__ void k_transpose_bf16(const float* __restrict__ in, bf16* __restrict__ out,
                                 int rows, int cols, long in_stride, long out_stride){
  __shared__ float tile[32][33];
  const float* inp = in + (size_t)blockIdx.z * in_stride;
  bf16* outp = out + (size_t)blockIdx.z * out_stride;
  int c0 = blockIdx.x*32, r0 = blockIdx.y*32;
  int tx = threadIdx.x, ty = threadIdx.y;
#pragma unroll
  for (int j = 0; j < 4; j++)
    tile[ty + j*8][tx] = inp[(size_t)(r0 + ty + j*8)*cols + c0 + tx];
  __syncthreads();
#pragma unroll
  for (int j = 0; j < 4; j++)
    outp[(size_t)(c0 + ty + j*8)*rows + r0 + tx] = __float2bfloat16(tile[tx][ty + j*8]);
}

// ---------------- fused: h = (embed | h+s0+s1); rmsnorm -> bf16 ----------------
__global__ void k_rmsnorm_fuse(const int* __restrict__ ids, const float* __restrict__ emb,
                               float* __restrict__ h, const float* __restrict__ s0,
                               const float* __restrict__ s1, const float* __restrict__ w,
                               bf16* __restrict__ u){
  int t = blockIdx.x;
  float* hp = h + (size_t)t*DM_;
  float v[4];
  float ss = 0.f;
#pragma unroll
  for (int j = 0; j < 4; j++){
    int i = threadIdx.x + j*256;
    float x;
    if (ids){ x = emb[(size_t)ids[t]*DM_ + i]; hp[i] = x; }
    else if (s0){ x = hp[i] + s0[(size_t)t*DM_ + i] + s1[(size_t)t*DM_ + i]; hp[i] = x; }
    else { x = hp[i]; }
    v[j] = x; ss += x*x;
  }
#pragma unroll
  for (int o = 32; o > 0; o >>= 1) ss += __shfl_down(ss, o, 64);
  __shared__ float red[4];
  if ((threadIdx.x & 63) == 0) red[threadIdx.x >> 6] = ss;
  __syncthreads();
  float tot = red[0]+red[1]+red[2]+red[3];
  float sc = rsqrtf(tot*(1.f/DM_) + EPS_);
  bf16* up = u + (size_t)t*DM_;
#pragma unroll
  for (int j = 0; j < 4; j++){
    int i = threadIdx.x + j*256;
    up[i] = __float2bfloat16(v[j]*sc*w[i]);
  }
}

// ---------------- bf16 MFMA GEMM, double-buffered LDS via global_load_lds ----------------
// A (M,K) bf16, Bt (N,K) bf16, C (M,N) f32.  BK=64, XOR-swizzled LDS.
// MODE 0: C=acc   1: C=softplus(acc+bias[col])   4: slab write C[z*M*N+idx]=acc
template<int BM, int BN, int NWM, int NWN, int MODE>
__global__ __launch_bounds__(256) void k_gemm(
    const short* __restrict__ A, const short* __restrict__ Bt, float* __restrict__ C,
    int M, int N, int K, int Ksplit, const float* __restrict__ bias)
{
  constexpr int BK = 64;
  constexpr int WM = BM/NWM, WN = BN/NWN;
  constexpr int MT = WM/16, NT = WN/16;
  constexpr int ABY = BM*BK*2, BBY = BN*BK*2;
  constexpr int AISS = ABY/4096, BISS = BBY/4096;
  __shared__ __align__(16) short As[2][BM*BK];
  __shared__ __align__(16) short Bs[2][BN*BK];
  int tid = threadIdx.x, lane = tid & 63, wave = tid >> 6;
  int wr = wave / NWN, wc = wave % NWN;
  int m0 = blockIdx.x * BM, n0 = blockIdx.y * BN;
  int lrow = lane & 15, lq = lane >> 4;
  int wbase = (tid & ~63) * 16;

  int kbeg = blockIdx.z * Ksplit;
  int nk = Ksplit / BK;

  f32x4 acc[MT][NT];
#pragma unroll
  for (int i = 0; i < MT; i++)
#pragma unroll
    for (int j = 0; j < NT; j++) acc[i][j] = (f32x4){0.f,0.f,0.f,0.f};

  auto stage = [&](int k0, int buf){
#pragma unroll
    for (int i = 0; i < AISS; i++){
      int off = i*4096 + tid*16;
      int row = off >> 7;
      int kc  = ((off >> 4) & 7) ^ (row & 7);
      gld_lds16(A + (size_t)(m0+row)*K + k0 + kc*8,
                As[buf] + ((i*4096 + wbase) >> 1));
    }
#pragma unroll
    for (int i = 0; i < BISS; i++){
      int off = i*4096 + tid*16;
      int row = off >> 7;
      int kc  = ((off >> 4) & 7) ^ (row & 7);
      gld_lds16(Bt + (size_t)(n0+row)*K + k0 + kc*8,
                Bs[buf] + ((i*4096 + wbase) >> 1));
    }
  };

  stage(kbeg, 0);
  __syncthreads();
  for (int it = 0; it < nk; it++){
    int cur = it & 1;
    if (it + 1 < nk) stage(kbeg + (it+1)*BK, cur ^ 1);
#pragma unroll
    for (int s = 0; s < 2; s++){
      bf16x8 af[MT], bfr[NT];
#pragma unroll
      for (int mt = 0; mt < MT; mt++){
        int row = wr*WM + mt*16 + lrow;
        int cc = (s*4 + lq) ^ (row & 7);
        af[mt] = *(const bf16x8*)(As[cur] + row*BK + cc*8);
      }
#pragma unroll
      for (int nt = 0; nt < NT; nt++){
        int row = wc*WN + nt*16 + lrow;
        int cc = (s*4 + lq) ^ (row & 7);
        bfr[nt] = *(const bf16x8*)(Bs[cur] + row*BK + cc*8);
      }
#pragma unroll
      for (int mt = 0; mt < MT; mt++)
#pragma unroll
        for (int nt = 0; nt < NT; nt++)
          acc[mt][nt] = __builtin_amdgcn_mfma_f32_16x16x32_bf16(af[mt], bfr[nt], acc[mt][nt], 0,0,0);
    }
    __syncthreads();
  }

  size_t slab = (MODE == 4) ? (size_t)blockIdx.z * M * N : 0;
#pragma unroll
  for (int mt = 0; mt < MT; mt++){
    int row = m0 + wr*WM + mt*16 + lq*4;
#pragma unroll
    for (int nt = 0; nt < NT; nt++){
      int col = n0 + wc*WN + nt*16 + lrow;
#pragma unroll
      for (int r = 0; r < 4; r++){
        float v = acc[mt][nt][r];
        size_t idx = slab + (size_t)(row + r)*N + col;
        if (MODE == 1) C[idx] = softplusf_(v + bias[col]);
        else C[idx] = v;
      }
    }
  }
}

// ---------------- causal depthwise conv(K=4) + bias + silu ----------------
__global__ void k_conv_silu(const float* __restrict__ xz, const float* __restrict__ cw,
                            const float* __restrict__ cb, float* __restrict__ xact,
                            bf16* __restrict__ xbf){
  int t = blockIdx.y;
  int e = blockIdx.x*256 + threadIdx.x;
  float4 w4 = *(const float4*)(cw + (size_t)e*4);
  float acc = cb[e];
  if (t >= 3){
    acc += xz[(size_t)(t-3)*E2 + e]*w4.x + xz[(size_t)(t-2)*E2 + e]*w4.y
         + xz[(size_t)(t-1)*E2 + e]*w4.z + xz[(size_t)t*E2 + e]*w4.w;
  } else {
    const float* wp = (const float*)&w4;
#pragma unroll
    for (int k = 0; k < 4; k++){ int tt = t-3+k; if (tt >= 0) acc += xz[(size_t)tt*E2 + e]*wp[k]; }
  }
  float xv = siluf_(acc);
  xact[(size_t)t*EE + e] = xv;
  xbf[(size_t)t*EE + e] = __float2bfloat16(xv);
}

// ---------------- reduce 8 Wx slabs -> xdbl f32 + xd64 bf16 ----------------
__global__ void k_reduce_xdbl(const float* __restrict__ s, float* __restrict__ out,
                              bf16* __restrict__ out64){
  int i = blockIdx.x*256 + threadIdx.x;    // < SEQ*NXD
  float v = 0.f;
#pragma unroll
  for (int c = 0; c < 8; c++) v += s[(size_t)c*SEQ*NXD + i];
  out[i] = v;
  int t = i / NXD, cc = i - t*NXD;
  if (cc < RNK) out64[(size_t)t*RNK + cc] = __float2bfloat16(v);
}

// ---------------- reduce 4 lm slabs -> d_out ----------------
__global__ void k_reduce_lm(const float* __restrict__ s, float* __restrict__ out){
  int i = blockIdx.x*256 + threadIdx.x;    // < SEQ*VOC
  float v = 0.f;
#pragma unroll
  for (int c = 0; c < 4; c++) v += s[(size_t)c*SEQ*VOC + i];
  out[i] = v;
}

// ---------------- scan phase A ----------------
__global__ void k_scanA(const float* __restrict__ dt, const float* __restrict__ x,
                        const float* __restrict__ xdbl, const float* __restrict__ Alog,
                        float* __restrict__ S, float* __restrict__ dtsum){
  int e = blockIdx.x*256 + threadIdx.x;
  int c = blockIdx.y;
  int t0 = c*CLEN;
  float Ae[NST];
#pragma unroll
  for (int n = 0; n < NST; n++) Ae[n] = -__expf(Alog[(size_t)e*NST + n]);
  __shared__ float Bsm[CLEN][NST];
  for (int i = threadIdx.x; i < CLEN*NST; i += 256)
    Bsm[i>>4][i&15] = xdbl[(size_t)(t0 + (i>>4))*NXD + RNK + (i&15)];
  __syncthreads();
  float h[NST];
#pragma unroll
  for (int n = 0; n < NST; n++) h[n] = 0.f;
  float ds = 0.f;
  for (int tt = 0; tt < CLEN; tt++){
    float dtv = dt[(size_t)(t0+tt)*EE + e];
    float xv  = x[(size_t)(t0+tt)*EE + e];
    ds += dtv;
    float sx = dtv * xv;
#pragma unroll
    for (int n = 0; n < NST; n++)
      h[n] = __expf(dtv*Ae[n])*h[n] + sx*Bsm[tt][n];
  }
  float* Sp = S + ((size_t)c*EE + e)*NST;
#pragma unroll
  for (int n = 0; n < NST; n++) Sp[n] = h[n];
  dtsum[(size_t)c*EE + e] = ds;
}

// ---------------- scan phase B: stitch ----------------
__global__ void k_scanB(const float* __restrict__ S, const float* __restrict__ dtsum,
                        const float* __restrict__ Alog, float* __restrict__ hinit){
  int idx = blockIdx.x*256 + threadIdx.x;   // e*16+n
  float An = -__expf(Alog[idx]);
  int e = idx >> 4;
  float h = 0.f;
  for (int c = 0; c < NCH; c++){
    hinit[(size_t)c*EE*NST + idx] = h;
    h = __expf(dtsum[(size_t)c*EE + e]*An)*h + S[(size_t)c*EE*NST + idx];
  }
}

// ---------------- scan phase C ----------------
__global__ void k_scanC(const float* __restrict__ dt, const float* __restrict__ x,
                        const float* __restrict__ xdbl, const float* __restrict__ Alog,
                        const float* __restrict__ Dp, const float* __restrict__ hinit,
                        const float* __restrict__ xz, bf16* __restrict__ ybf){
  int e = blockIdx.x*256 + threadIdx.x;
  int c = blockIdx.y;
  int t0 = c*CLEN;
  float Ae[NST];
#pragma unroll
  for (int n = 0; n < NST; n++) Ae[n] = -__expf(Alog[(size_t)e*NST + n]);
  __shared__ float Bsm[CLEN][NST], Csm[CLEN][NST];
  for (int i = threadIdx.x; i < CLEN*NST; i += 256){
    int tt = i>>4, n = i&15;
    Bsm[tt][n] = xdbl[(size_t)(t0+tt)*NXD + RNK + n];
    Csm[tt][n] = xdbl[(size_t)(t0+tt)*NXD + RNK + NST + n];
  }
  __syncthreads();
  float h[NST];
  const float* hp = hinit + ((size_t)c*EE + e)*NST;
#pragma unroll
  for (int n = 0; n < NST; n++) h[n] = hp[n];
  float Dv = Dp[e];
  for (int tt = 0; tt < CLEN; tt++){
    float dtv = dt[(size_t)(t0+tt)*EE + e];
    float xv  = x[(size_t)(t0+tt)*EE + e];
    float sx = dtv*xv;
    float y = Dv*xv;
#pragma unroll
    for (int n = 0; n < NST; n++){
      h[n] = __expf(dtv*Ae[n])*h[n] + sx*Bsm[tt][n];
      y += h[n]*Csm[tt][n];
    }
    float zv = xz[(size_t)(t0+tt)*E2 + EE + e];
    y *= zv*sigmoidf_(zv);
    ybf[(size_t)(t0+tt)*EE + e] = __float2bfloat16(y);
  }
}

// ---------------- launch ----------------
extern "C" void kernel_launch(void* const* d_in, const int* in_sizes, int n_in,
                              void* d_out, int out_size, void* d_ws, size_t ws_size,
                              hipStream_t stream)
{
  const int*   ids  = (const int*)d_in[0];
  const float* emb  = (const float*)d_in[1];
  const float* Wxz  = (const float*)d_in[2];
  const float* cw   = (const float*)d_in[3];
  const float* cb   = (const float*)d_in[4];
  const float* Wx   = (const float*)d_in[5];
  const float* Wdt  = (const float*)d_in[6];
  const float* dtb  = (const float*)d_in[7];
  const float* Alog = (const float*)d_in[8];
  const float* Dp   = (const float*)d_in[9];
  const float* Wout = (const float*)d_in[10];
  const float* nw   = (const float*)d_in[11];
  const float* fnw  = (const float*)d_in[12];
  const float* lmw  = (const float*)d_in[13];

  char* p = (char*)d_ws;
  auto alloc = [&](size_t bytes){ void* r = (void*)p; p += (bytes + 255) & ~(size_t)255; return r; };
  bf16* wxz_bf  = (bf16*)alloc((size_t)NLAY*E2*DM_*2);
  bf16* wout_bf = (bf16*)alloc((size_t)NLAY*DM_*EE*2);
  bf16* wx_bf   = (bf16*)alloc((size_t)NLAY*NXD*EE*2);
  bf16* wdt_bf  = (bf16*)alloc((size_t)NLAY*EE*RNK*2);
  bf16* lm_bf   = (bf16*)alloc((size_t)VOC*DM_*2);
  float* h      = (float*)alloc((size_t)SEQ*DM_*4);
  float* hslab  = (float*)alloc((size_t)2*SEQ*DM_*4);
  bf16* u_bf    = (bf16*)alloc((size_t)SEQ*DM_*2);
  float* xzb    = (float*)alloc((size_t)SEQ*E2*4);
  float* xact   = (float*)alloc((size_t)SEQ*EE*4);
  bf16* x_bf    = (bf16*)alloc((size_t)SEQ*EE*2);
  float* xdbl_s = (float*)alloc((size_t)8*SEQ*NXD*4);
  float* xdbl   = (float*)alloc((size_t)SEQ*NXD*4);
  bf16* xd64    = (bf16*)alloc((size_t)SEQ*RNK*2);
  float* dtbuf  = (float*)alloc((size_t)SEQ*EE*4);
  float* Sbuf   = (float*)alloc((size_t)NCH*EE*NST*4);
  float* dtsum  = (float*)alloc((size_t)NCH*EE*4);
  float* hinit  = (float*)alloc((size_t)NCH*EE*NST*4);
  bf16* y_bf    = (bf16*)alloc((size_t)SEQ*EE*2);
  float* lmslab = (float*)alloc((size_t)4*SEQ*VOC*4);

  // weight conversion (per launch; weights -> bf16 B^T layout)
  k_transpose_bf16<<<dim3(E2/32, DM_/32, NLAY), dim3(32,8), 0, stream>>>(Wxz, wxz_bf, DM_, E2, (long)DM_*E2, (long)E2*DM_);
  k_transpose_bf16<<<dim3(DM_/32, EE/32, NLAY), dim3(32,8), 0, stream>>>(Wout, wout_bf, EE, DM_, (long)EE*DM_, (long)DM_*EE);
  k_transpose_bf16<<<dim3(NXD/32, EE/32, NLAY), dim3(32,8), 0, stream>>>(Wx, wx_bf, EE, NXD, (long)EE*NXD, (long)NXD*EE);
  k_transpose_bf16<<<dim3(EE/32, RNK/32, NLAY), dim3(32,8), 0, stream>>>(Wdt, wdt_bf, RNK, EE, (long)RNK*EE, (long)EE*RNK);
  k_transpose_bf16<<<dim3(VOC/32, DM_/32, 1), dim3(32,8), 0, stream>>>(lmw, lm_bf, DM_, VOC, 0, 0);

  for (int l = 0; l < NLAY; l++){
    k_rmsnorm_fuse<<<SEQ, 256, 0, stream>>>(
        l == 0 ? ids : nullptr, emb, h,
        l == 0 ? nullptr : hslab, hslab + (size_t)SEQ*DM_,
        nw + (size_t)l*DM_, u_bf);
    k_gemm<128,64,2,2,0><<<dim3(SEQ/128, E2/64, 1), 256, 0, stream>>>(
        (const short*)u_bf, (const short*)(wxz_bf + (size_t)l*E2*DM_), xzb,
        SEQ, E2, DM_, DM_, nullptr);
    k_conv_silu<<<dim3(EE/256, SEQ), 256, 0, stream>>>(
        xzb, cw + (size_t)l*EE*KCONV, cb + (size_t)l*EE, xact, x_bf);
    k_gemm<32,96,2,2,4><<<dim3(SEQ/32, 1, 8), 256, 0, stream>>>(
        (const short*)x_bf, (const short*)(wx_bf + (size_t)l*NXD*EE), xdbl_s,
        SEQ, NXD, EE, EE/8, nullptr);
    k_reduce_xdbl<<<SEQ*NXD/256, 256, 0, stream>>>(xdbl_s, xdbl, xd64);
    k_gemm<64,64,2,2,1><<<dim3(SEQ/64, EE/64, 1), 256, 0, stream>>>(
        (const short*)xd64, (const short*)(wdt_bf + (size_t)l*EE*RNK), dtbuf,
        SEQ, EE, RNK, RNK, dtb + (size_t)l*EE);
    k_scanA<<<dim3(EE/256, NCH), 256, 0, stream>>>(
        dtbuf, xact, xdbl, Alog + (size_t)l*EE*NST, Sbuf, dtsum);
    k_scanB<<<dim3(EE*NST/256), 256, 0, stream>>>(Sbuf, dtsum, Alog + (size_t)l*EE*NST, hinit);
    k_scanC<<<dim3(EE/256, NCH), 256, 0, stream>>>(
        dtbuf, xact, xdbl, Alog + (size_t)l*EE*NST, Dp + (size_t)l*EE, hinit, xzb, y_bf);
    k_gemm<64,64,2,2,4><<<dim3(SEQ/64, DM_/64, 2), 256, 0, stream>>>(
        (const short*)y_bf, (const short*)(wout_bf + (size_t)l*DM_*EE), hslab,
        SEQ, DM_, EE, EE/2, nullptr);
  }
  k_rmsnorm_fuse<<<SEQ, 256, 0, stream>>>(
      nullptr, emb, h, hslab, hslab + (size_t)SEQ*DM_, fnw, u_bf);
  k_gemm<64,64,2,2,4><<<dim3(SEQ/64, VOC/64, 4), 256, 0, stream>>>(
      (const short*)u_bf, (const short*)lm_bf, lmslab,
      SEQ, VOC, DM_, DM_/4, nullptr);
  k_reduce_lm<<<SEQ*VOC/256, 256, 0, stream>>>(lmslab, (float*)d_out);
}